// Round 4
// baseline (141.049 us; speedup 1.0000x reference)
//
#include <hip/hip_runtime.h>
#include <math.h>

#define N_ATOMS   8192
#define N_MOLS    64
#define K_NBRS    32
#define CUTOFF2   100.0f
#define MAX_PER_LANE 16   // supports molecule size up to 64*16 = 1024 (actual ~128)

// ---------------------------------------------------------------------------
// Kernel 1: molecule start offsets. batch is sorted, so molecule m occupies
// [mol_start[m], mol_start[m+1]). Thread m does a lower_bound binary search.
// ---------------------------------------------------------------------------
__global__ void mol_start_kernel(const int* __restrict__ batch,
                                 int* __restrict__ mol_start) {
    int m = blockIdx.x * blockDim.x + threadIdx.x;
    if (m > N_MOLS) return;
    int lo = 0, hi = N_ATOMS;
    while (lo < hi) {
        int mid = (lo + hi) >> 1;
        if (batch[mid] < m) lo = mid + 1; else hi = mid;
    }
    mol_start[m] = lo;
}

// ---------------------------------------------------------------------------
// Kernel 2: one 64-lane wave per atom.
//  - candidates = same-molecule atoms (contiguous range), lane-strided
//  - sq computed with the reference's exact f32 arithmetic:
//      sqn   = ((x*x + y*y) + z*z)                 (numpy squares-then-sum)
//      dot   = fma(z_i,z_j, fma(y_i,y_j, x_i*x_j)) (BLAS k-sequential FMA)
//      sq    = (sqn_i + sqn_j) - 2*dot
//  - K=32 selection passes: min over keys (sq, idx) lexicographically greater
//    than the last selected key (no used-marking), butterfly-reduced.
//  - lane k holds result k; lanes 0..31 write coalesced.
// ---------------------------------------------------------------------------
__global__ __launch_bounds__(256) void radius_graph_kernel(
        const float* __restrict__ pos,
        const int*   __restrict__ batch,
        const int*   __restrict__ mol_start,
        float*       __restrict__ out) {
    const int wave = (blockIdx.x * blockDim.x + threadIdx.x) >> 6;
    const int lane = threadIdx.x & 63;
    const int i = wave;
    if (i >= N_ATOMS) return;

    const float xi = pos[3 * i + 0];
    const float yi = pos[3 * i + 1];
    const float zi = pos[3 * i + 2];
    const float sqn_i = __fadd_rn(__fadd_rn(__fmul_rn(xi, xi), __fmul_rn(yi, yi)),
                                  __fmul_rn(zi, zi));

    const int b = batch[i];
    const int s = mol_start[b];
    const int e = mol_start[b + 1];
    const int cands = e - s;
    const int C = (cands + 63) >> 6;   // candidates per lane (ceil)

    // Per-lane candidate squared distances (INF = invalid). Index of slot c
    // is recomputed as s + lane + 64*c, so only sq needs storage.
    float csq[MAX_PER_LANE];
#pragma unroll
    for (int c = 0; c < MAX_PER_LANE; ++c) csq[c] = INFINITY;

#pragma unroll
    for (int c = 0; c < MAX_PER_LANE; ++c) {
        const int j = s + lane + (c << 6);
        if (c < C && j < e && j != i) {
            const float xj = pos[3 * j + 0];
            const float yj = pos[3 * j + 1];
            const float zj = pos[3 * j + 2];
            const float sqn_j = __fadd_rn(__fadd_rn(__fmul_rn(xj, xj),
                                                    __fmul_rn(yj, yj)),
                                          __fmul_rn(zj, zj));
            const float dot = __fmaf_rn(zi, zj,
                              __fmaf_rn(yi, yj,
                              __fmul_rn(xi, xj)));
            const float sq = __fsub_rn(__fadd_rn(sqn_i, sqn_j),
                                       __fmul_rn(2.0f, dot));
            if (sq <= CUTOFF2) csq[c] = sq;
        }
    }

    // Selection: k-th nearest = min over keys > last selected key.
    float last_sq = -INFINITY;
    int   last_idx = -1;
    float my_col = (float)i;   // lane k's result for slot k (defaults = pad)
    float my_w   = 0.0f;
    float my_msk = 0.0f;

    for (int k = 0; k < K_NBRS; ++k) {
        float msq = INFINITY;
        int   midx = 0x7fffffff;
#pragma unroll
        for (int c = 0; c < MAX_PER_LANE; ++c) {
            const float sq = csq[c];
            const int   j  = s + lane + (c << 6);
            const bool gt = (sq > last_sq) || (sq == last_sq && j > last_idx);
            const bool lt = (sq < msq) || (sq == msq && j < midx);
            if (gt && lt) { msq = sq; midx = j; }
        }
        // 64-lane butterfly min with (sq, idx) lexicographic tie-break
        for (int off = 32; off; off >>= 1) {
            const float osq  = __shfl_xor(msq, off);
            const int   oidx = __shfl_xor(midx, off);
            if (osq < msq || (osq == msq && oidx < midx)) { msq = osq; midx = oidx; }
        }
        if (msq < INFINITY) {
            if (lane == k) {
                my_col = (float)midx;
                // exact edge weight: d = pos[i]-pos[j]; sqrt(max(sum d*d,1e-12))
                const float xj = pos[3 * midx + 0];
                const float yj = pos[3 * midx + 1];
                const float zj = pos[3 * midx + 2];
                const float dx = __fsub_rn(xi, xj);
                const float dy = __fsub_rn(yi, yj);
                const float dz = __fsub_rn(zi, zj);
                const float s2 = __fadd_rn(__fadd_rn(__fmul_rn(dx, dx),
                                                     __fmul_rn(dy, dy)),
                                           __fmul_rn(dz, dz));
                my_w   = __fsqrt_rn(fmaxf(s2, 1e-12f));
                my_msk = 1.0f;
            }
            last_sq = msq;
            last_idx = midx;
        } else {
            break;   // uniform across wave; remaining slots keep pad defaults
        }
    }

    // Output layout (float32): row | col | weight | mask, each N*K
    const int NK = N_ATOMS * K_NBRS;
    if (lane < K_NBRS) {
        const int o = i * K_NBRS + lane;
        out[o]          = (float)i;   // row
        out[NK + o]     = my_col;     // col
        out[2 * NK + o] = my_w;       // weight
        out[3 * NK + o] = my_msk;     // mask
    }
}

extern "C" void kernel_launch(void* const* d_in, const int* in_sizes, int n_in,
                              void* d_out, int out_size, void* d_ws, size_t ws_size,
                              hipStream_t stream) {
    const float* pos   = (const float*)d_in[0];
    const int*   batch = (const int*)d_in[1];
    float*       out   = (float*)d_out;
    int*         mol_start = (int*)d_ws;   // 65 ints

    mol_start_kernel<<<1, 128, 0, stream>>>(batch, mol_start);
    radius_graph_kernel<<<N_ATOMS / 4, 256, 0, stream>>>(pos, batch, mol_start, out);
}

// Round 5
// 37.765 us; speedup vs baseline: 3.7349x; 3.7349x over previous
//
#include <hip/hip_runtime.h>
#include <math.h>

#define N_ATOMS   8192
#define N_MOLS    64
#define K_NBRS    32
#define CUTOFF2   100.0f
#define MAX_SLOTS 4              // supports molecules up to 256 atoms (actual ~128 +- 11)
#define INVALID_SQB 0xFFFFFFFFu  // sentinel sq-bits for invalid candidates

// ---------------------------------------------------------------------------
// Kernel 1: molecule start offsets. batch is sorted, so molecule m occupies
// [mol_start[m], mol_start[m+1]). Thread m does a lower_bound binary search.
// ---------------------------------------------------------------------------
__global__ void mol_start_kernel(const int* __restrict__ batch,
                                 int* __restrict__ mol_start) {
    int m = blockIdx.x * blockDim.x + threadIdx.x;
    if (m > N_MOLS) return;
    int lo = 0, hi = N_ATOMS;
    while (lo < hi) {
        int mid = (lo + hi) >> 1;
        if (batch[mid] < m) lo = mid + 1; else hi = mid;
    }
    mol_start[m] = lo;
}

// ---------------------------------------------------------------------------
// Kernel 2: one 64-lane wave per atom, rank-based top-K selection.
//  Phase 1: each lane computes sq for its <=4 lane-strided candidates with the
//           reference's exact f32 arithmetic:
//             sqn = ((x*x + y*y) + z*z)                  (numpy squares-then-sum)
//             dot = fma(z,z, fma(y,y, x*x))              (k-sequential FMA)
//             sq  = (sqn_i + sqn_j) - 2*dot
//           key64 = (sq_bits << 8) | slot_pos  -- strict total order matching
//           stable top_k's (sq asc, index asc).
//  Phase 2: single pass over all candidates t: broadcast sq_bits via readlane
//           (SGPR), build kt64 in SALU, rank[c] += (kt64 < key64[c]).
//  Phase 3: valid candidates with rank<K scatter their index into per-wave LDS;
//           lanes 0..31 read back, recompute exact ref weight from gathered
//           positions, store coalesced. Pad slots keep col=i, w=0, mask=0.
// ---------------------------------------------------------------------------
__global__ __launch_bounds__(256) void radius_graph_kernel(
        const float* __restrict__ pos,
        const int*   __restrict__ batch,
        const int*   __restrict__ mol_start,
        float*       __restrict__ out) {
    __shared__ int lds_col[4][K_NBRS];

    const int wid  = threadIdx.x >> 6;     // wave within block
    const int lane = threadIdx.x & 63;
    const int i = blockIdx.x * 4 + wid;    // grid is exactly N_ATOMS/4 blocks

    const float xi = pos[3 * i + 0];
    const float yi = pos[3 * i + 1];
    const float zi = pos[3 * i + 2];
    const float sqn_i = __fadd_rn(__fadd_rn(__fmul_rn(xi, xi), __fmul_rn(yi, yi)),
                                  __fmul_rn(zi, zi));

    const int b = batch[i];
    const int s = mol_start[b];
    const int e = mol_start[b + 1];
    const int cands  = e - s;
    const int nslots = (cands + 63) >> 6;  // wave-uniform

    // -------- Phase 1: per-lane candidate keys --------
    unsigned sqb[MAX_SLOTS];               // sq float bits (for readlane broadcast)
    unsigned long long key64[MAX_SLOTS];   // (sqb<<8)|slot_pos, ~0 for invalid
#pragma unroll
    for (int c = 0; c < MAX_SLOTS; ++c) {
        sqb[c]   = INVALID_SQB;
        key64[c] = ~0ull;
        const int me = lane + (c << 6);    // slot position = j - s, < 256
        const int j  = s + me;
        if (j < e && j != i) {
            const float xj = pos[3 * j + 0];
            const float yj = pos[3 * j + 1];
            const float zj = pos[3 * j + 2];
            const float sqn_j = __fadd_rn(__fadd_rn(__fmul_rn(xj, xj),
                                                    __fmul_rn(yj, yj)),
                                          __fmul_rn(zj, zj));
            const float dot = __fmaf_rn(zi, zj,
                              __fmaf_rn(yi, yj,
                              __fmul_rn(xi, xj)));
            const float sq = __fsub_rn(__fadd_rn(sqn_i, sqn_j),
                                       __fmul_rn(2.0f, dot));
            if (sq <= CUTOFF2) {
                const unsigned kb = __float_as_uint(fmaxf(sq, 0.0f));
                sqb[c]   = kb;
                key64[c] = ((unsigned long long)kb << 8) | (unsigned)me;
            }
        }
    }

    // -------- Phase 2: rank = # candidates with strictly smaller key --------
    unsigned rank[MAX_SLOTS];
#pragma unroll
    for (int c = 0; c < MAX_SLOTS; ++c) rank[c] = 0;

#pragma unroll
    for (int c2 = 0; c2 < MAX_SLOTS; ++c2) {
        if (c2 < nslots) {                 // wave-uniform branch
#pragma unroll
            for (int l = 0; l < 64; ++l) {
                const unsigned kt = __builtin_amdgcn_readlane(sqb[c2], l);
                const unsigned long long kt64 =
                    ((unsigned long long)kt << 8) | (unsigned)((c2 << 6) + l);
#pragma unroll
                for (int c = 0; c < MAX_SLOTS; ++c)
                    rank[c] += (kt64 < key64[c]) ? 1u : 0u;
            }
        }
    }

    // -------- Phase 3: scatter winners through LDS, coalesced writeback --------
    if (lane < K_NBRS) lds_col[wid][lane] = i;   // pad default: self loop
    __syncthreads();

#pragma unroll
    for (int c = 0; c < MAX_SLOTS; ++c) {
        if (sqb[c] != INVALID_SQB && rank[c] < K_NBRS)
            lds_col[wid][rank[c]] = s + lane + (c << 6);
    }
    __syncthreads();

    const int NK = N_ATOMS * K_NBRS;
    if (lane < K_NBRS) {
        const int j = lds_col[wid][lane];
        const bool real = (j != i);
        float w = 0.0f;
        if (real) {
            // exact ref weight: d = pos[i]-pos[j]; sqrt(max(((dx^2+dy^2)+dz^2),1e-12))
            const float xj = pos[3 * j + 0];
            const float yj = pos[3 * j + 1];
            const float zj = pos[3 * j + 2];
            const float dx = __fsub_rn(xi, xj);
            const float dy = __fsub_rn(yi, yj);
            const float dz = __fsub_rn(zi, zj);
            const float s2 = __fadd_rn(__fadd_rn(__fmul_rn(dx, dx),
                                                 __fmul_rn(dy, dy)),
                                       __fmul_rn(dz, dz));
            w = __fsqrt_rn(fmaxf(s2, 1e-12f));
        }
        const int o = i * K_NBRS + lane;
        out[o]          = (float)i;          // row
        out[NK + o]     = (float)j;          // col
        out[2 * NK + o] = w;                 // weight
        out[3 * NK + o] = real ? 1.0f : 0.0f; // mask
    }
}

extern "C" void kernel_launch(void* const* d_in, const int* in_sizes, int n_in,
                              void* d_out, int out_size, void* d_ws, size_t ws_size,
                              hipStream_t stream) {
    const float* pos   = (const float*)d_in[0];
    const int*   batch = (const int*)d_in[1];
    float*       out   = (float*)d_out;
    int*         mol_start = (int*)d_ws;   // 65 ints

    mol_start_kernel<<<1, 128, 0, stream>>>(batch, mol_start);
    radius_graph_kernel<<<N_ATOMS / 4, 256, 0, stream>>>(pos, batch, mol_start, out);
}

// Round 6
// 26.843 us; speedup vs baseline: 5.2546x; 1.4069x over previous
//
#include <hip/hip_runtime.h>
#include <math.h>

#define N_ATOMS   8192
#define N_MOLS    64
#define K_NBRS    32
#define CUTOFF2   100.0f
#define MAX_SLOTS 4              // supports molecules up to 256 atoms (actual ~128 +- 11)
#define INVALID_SQB 0xFFFFFFFFu  // sentinel sq-bits for invalid candidates

// ---------------------------------------------------------------------------
// rank_pass<NS>: for each of this lane's NS resident candidates, count how many
// of the molecule's NS*64 candidates have a strictly smaller 64-bit key.
// Broadcast via readlane (wave-uniform SGPR), compare per-lane (v_cmp_lt_u64 +
// addc). Invalid candidates carry key ~0 and never win a compare.
// ---------------------------------------------------------------------------
template<int NS>
__device__ __forceinline__ void rank_pass(const unsigned* sqb,
                                          const unsigned long long* key64,
                                          unsigned* rank) {
#pragma unroll
    for (int c2 = 0; c2 < NS; ++c2) {
#pragma unroll
        for (int l = 0; l < 64; ++l) {
            const unsigned kt = __builtin_amdgcn_readlane(sqb[c2], l);
            const unsigned long long kt64 =
                ((unsigned long long)kt << 8) | (unsigned)((c2 << 6) + l);
#pragma unroll
            for (int c = 0; c < NS; ++c)
                rank[c] += (kt64 < key64[c]) ? 1u : 0u;
        }
    }
}

// ---------------------------------------------------------------------------
// One 64-lane wave per atom, rank-based top-K selection.
//  Phase 0: molecule range [s,e) via ballot-window scan of sorted batch
//           (molecule size <= 256, proven by round-5 pass with 4 slots).
//  Phase 1: per-lane candidate keys, reference-exact f32 arithmetic:
//             sqn = ((x*x + y*y) + z*z)           (numpy squares-then-sum)
//             dot = fma(z,z, fma(y,y, x*x))       (k-sequential FMA)
//             sq  = (sqn_i + sqn_j) - 2*dot
//           key64 = (sq_bits << 8) | slot_pos  -- strict total order matching
//           stable top_k (sq asc, index asc).
//  Phase 2: rank_pass specialized on nslots (wave-uniform).
//  Phase 3: winners (rank < K) scatter col index into wave-private LDS;
//           lanes 0..31 read back, recompute exact ref weight, store coalesced.
// ---------------------------------------------------------------------------
__global__ __launch_bounds__(256) void radius_graph_kernel(
        const float* __restrict__ pos,
        const int*   __restrict__ batch,
        float*       __restrict__ out) {
    __shared__ int lds_col[4][K_NBRS];

    const int wid  = threadIdx.x >> 6;     // wave within block
    const int lane = threadIdx.x & 63;
    const int i = blockIdx.x * 4 + wid;    // grid is exactly N_ATOMS/4 blocks

    const float xi = pos[3 * i + 0];
    const float yi = pos[3 * i + 1];
    const float zi = pos[3 * i + 2];
    const float sqn_i = __fadd_rn(__fadd_rn(__fmul_rn(xi, xi), __fmul_rn(yi, yi)),
                                  __fmul_rn(zi, zi));

    // -------- Phase 0: molecule range via ballot-window scan --------
    const int b = batch[i];
    int cnt_b4 = 0, cnt_af = 0;
#pragma unroll
    for (int c = 0; c < 4; ++c) {
        const int jb = i - 256 + (c << 6) + lane;   // window [i-256, i-1]
        const int ja = i + 1   + (c << 6) + lane;   // window [i+1, i+256]
        int vb = -1, va = -2;
        if (jb >= 0)      vb = batch[jb];
        if (ja < N_ATOMS) va = batch[ja];
        cnt_b4 += (int)__popcll(__ballot(vb == b));
        cnt_af += (int)__popcll(__ballot(va == b));
    }
    const int s = i - cnt_b4;               // lower_bound(batch, b)
    const int e = i + 1 + cnt_af;           // lower_bound(batch, b+1)
    const int cands  = e - s;
    const int nslots = (cands + 63) >> 6;   // wave-uniform, <= 4

    // -------- Phase 1: per-lane candidate keys --------
    unsigned sqb[MAX_SLOTS];               // sq float bits (for readlane broadcast)
    unsigned long long key64[MAX_SLOTS];   // (sqb<<8)|slot_pos, ~0 for invalid
#pragma unroll
    for (int c = 0; c < MAX_SLOTS; ++c) {
        sqb[c]   = INVALID_SQB;
        key64[c] = ~0ull;
        const int me = lane + (c << 6);    // slot position = j - s, < 256
        const int j  = s + me;
        if (j < e && j != i) {
            const float xj = pos[3 * j + 0];
            const float yj = pos[3 * j + 1];
            const float zj = pos[3 * j + 2];
            const float sqn_j = __fadd_rn(__fadd_rn(__fmul_rn(xj, xj),
                                                    __fmul_rn(yj, yj)),
                                          __fmul_rn(zj, zj));
            const float dot = __fmaf_rn(zi, zj,
                              __fmaf_rn(yi, yj,
                              __fmul_rn(xi, xj)));
            const float sq = __fsub_rn(__fadd_rn(sqn_i, sqn_j),
                                       __fmul_rn(2.0f, dot));
            if (sq <= CUTOFF2) {
                const unsigned kb = __float_as_uint(fmaxf(sq, 0.0f));
                sqb[c]   = kb;
                key64[c] = ((unsigned long long)kb << 8) | (unsigned)me;
            }
        }
    }

    // -------- Phase 2: ranks, specialized on nslots --------
    unsigned rank[MAX_SLOTS];
#pragma unroll
    for (int c = 0; c < MAX_SLOTS; ++c) rank[c] = 0;

    if (nslots <= 2)      rank_pass<2>(sqb, key64, rank);
    else if (nslots == 3) rank_pass<3>(sqb, key64, rank);
    else                  rank_pass<4>(sqb, key64, rank);

    // -------- Phase 3: scatter winners through wave-private LDS --------
    if (lane < K_NBRS) lds_col[wid][lane] = i;   // pad default: self loop
    // same-wave LDS ordering is guaranteed; no cross-wave sharing -> no barrier
#pragma unroll
    for (int c = 0; c < MAX_SLOTS; ++c) {
        if (sqb[c] != INVALID_SQB && rank[c] < K_NBRS)
            lds_col[wid][rank[c]] = s + lane + (c << 6);
    }

    const int NK = N_ATOMS * K_NBRS;
    if (lane < K_NBRS) {
        const int j = lds_col[wid][lane];
        const bool real = (j != i);
        float w = 0.0f;
        if (real) {
            // exact ref weight: d = pos[i]-pos[j]; sqrt(max(((dx^2+dy^2)+dz^2),1e-12))
            const float xj = pos[3 * j + 0];
            const float yj = pos[3 * j + 1];
            const float zj = pos[3 * j + 2];
            const float dx = __fsub_rn(xi, xj);
            const float dy = __fsub_rn(yi, yj);
            const float dz = __fsub_rn(zi, zj);
            const float s2 = __fadd_rn(__fadd_rn(__fmul_rn(dx, dx),
                                                 __fmul_rn(dy, dy)),
                                       __fmul_rn(dz, dz));
            w = __fsqrt_rn(fmaxf(s2, 1e-12f));
        }
        const int o = i * K_NBRS + lane;
        out[o]          = (float)i;           // row
        out[NK + o]     = (float)j;           // col
        out[2 * NK + o] = w;                  // weight
        out[3 * NK + o] = real ? 1.0f : 0.0f; // mask
    }
}

extern "C" void kernel_launch(void* const* d_in, const int* in_sizes, int n_in,
                              void* d_out, int out_size, void* d_ws, size_t ws_size,
                              hipStream_t stream) {
    const float* pos   = (const float*)d_in[0];
    const int*   batch = (const int*)d_in[1];
    float*       out   = (float*)d_out;

    radius_graph_kernel<<<N_ATOMS / 4, 256, 0, stream>>>(pos, batch, out);
}

// Round 7
// 22.425 us; speedup vs baseline: 6.2898x; 1.1970x over previous
//
#include <hip/hip_runtime.h>
#include <math.h>

#define N_ATOMS   8192
#define N_MOLS    64
#define K_NBRS    32
#define CUTOFF2   100.0f
#define MAX_SLOTS 4              // supports molecules up to 256 atoms (actual ~128 +- 11)
#define INVALID_SQB 0xFFFFFFFFu  // sentinel sq-bits for invalid candidates

// ---------------------------------------------------------------------------
// rank_pass<NS>: for each of this lane's NS resident candidates, count how many
// of the molecule's candidates have a strictly smaller 64-bit key. Broadcast
// via readlane (wave-uniform SGPR lane from ballot+ctz, skipping invalid
// candidates entirely), compare per-lane (v_cmp_lt_u64 + addc). Invalid
// resident candidates carry key ~0 and never win a compare.
// ---------------------------------------------------------------------------
template<int NS>
__device__ __forceinline__ void rank_pass(const unsigned* sqb,
                                          const unsigned long long* key64,
                                          unsigned* rank) {
#pragma unroll
    for (int c2 = 0; c2 < NS; ++c2) {
        unsigned long long m = __ballot(sqb[c2] != INVALID_SQB);
        while (m) {
            const int l = __builtin_ctzll(m);   // wave-uniform (SALU)
            m &= m - 1;
            const unsigned kt = __builtin_amdgcn_readlane(sqb[c2], l);
            const unsigned long long kt64 =
                ((unsigned long long)kt << 8) | (unsigned)((c2 << 6) + l);
#pragma unroll
            for (int c = 0; c < NS; ++c)
                rank[c] += (kt64 < key64[c]) ? 1u : 0u;
        }
    }
}

// ---------------------------------------------------------------------------
// One 64-lane wave per atom, rank-based top-K selection.
//  Phase 0: molecule range [s,e) via ballot-window scan of sorted batch
//           (molecule size <= 256, proven by round-5 pass with 4 slots).
//  Phase 1: per-lane candidate keys, reference-exact f32 arithmetic:
//             sqn = ((x*x + y*y) + z*z)           (numpy squares-then-sum)
//             dot = fma(z,z, fma(y,y, x*x))       (k-sequential FMA)
//             sq  = (sqn_i + sqn_j) - 2*dot
//           key64 = (sq_bits << 8) | slot_pos  -- strict total order matching
//           stable top_k (sq asc, index asc).
//  Phase 2: rank_pass specialized on nslots (wave-uniform), valid-compacted.
//  Phase 3: winners (rank < K) scatter col index into wave-private LDS;
//           lanes 0..31 read back, recompute exact ref weight, store coalesced.
// ---------------------------------------------------------------------------
__global__ __launch_bounds__(256) void radius_graph_kernel(
        const float* __restrict__ pos,
        const int*   __restrict__ batch,
        float*       __restrict__ out) {
    __shared__ int lds_col[4][K_NBRS];

    const int wid  = threadIdx.x >> 6;     // wave within block
    const int lane = threadIdx.x & 63;
    const int i = blockIdx.x * 4 + wid;    // grid is exactly N_ATOMS/4 blocks

    const float xi = pos[3 * i + 0];
    const float yi = pos[3 * i + 1];
    const float zi = pos[3 * i + 2];
    const float sqn_i = __fadd_rn(__fadd_rn(__fmul_rn(xi, xi), __fmul_rn(yi, yi)),
                                  __fmul_rn(zi, zi));

    // -------- Phase 0: molecule range via ballot-window scan --------
    const int b = batch[i];
    int cnt_b4 = 0, cnt_af = 0;
#pragma unroll
    for (int c = 0; c < 4; ++c) {
        const int jb = i - 256 + (c << 6) + lane;   // window [i-256, i-1]
        const int ja = i + 1   + (c << 6) + lane;   // window [i+1, i+256]
        int vb = -1, va = -2;
        if (jb >= 0)      vb = batch[jb];
        if (ja < N_ATOMS) va = batch[ja];
        cnt_b4 += (int)__popcll(__ballot(vb == b));
        cnt_af += (int)__popcll(__ballot(va == b));
    }
    const int s = i - cnt_b4;               // lower_bound(batch, b)
    const int e = i + 1 + cnt_af;           // lower_bound(batch, b+1)
    const int cands  = e - s;
    const int nslots = (cands + 63) >> 6;   // wave-uniform, <= 4

    // -------- Phase 1: per-lane candidate keys --------
    unsigned sqb[MAX_SLOTS];               // sq float bits (for readlane broadcast)
    unsigned long long key64[MAX_SLOTS];   // (sqb<<8)|slot_pos, ~0 for invalid
#pragma unroll
    for (int c = 0; c < MAX_SLOTS; ++c) {
        sqb[c]   = INVALID_SQB;
        key64[c] = ~0ull;
        const int me = lane + (c << 6);    // slot position = j - s, < 256
        const int j  = s + me;
        if (j < e && j != i) {
            const float xj = pos[3 * j + 0];
            const float yj = pos[3 * j + 1];
            const float zj = pos[3 * j + 2];
            const float sqn_j = __fadd_rn(__fadd_rn(__fmul_rn(xj, xj),
                                                    __fmul_rn(yj, yj)),
                                          __fmul_rn(zj, zj));
            const float dot = __fmaf_rn(zi, zj,
                              __fmaf_rn(yi, yj,
                              __fmul_rn(xi, xj)));
            const float sq = __fsub_rn(__fadd_rn(sqn_i, sqn_j),
                                       __fmul_rn(2.0f, dot));
            if (sq <= CUTOFF2) {
                const unsigned kb = __float_as_uint(fmaxf(sq, 0.0f));
                sqb[c]   = kb;
                key64[c] = ((unsigned long long)kb << 8) | (unsigned)me;
            }
        }
    }

    // -------- Phase 2: ranks, specialized on nslots, valid-compacted --------
    unsigned rank[MAX_SLOTS];
#pragma unroll
    for (int c = 0; c < MAX_SLOTS; ++c) rank[c] = 0;

    if (nslots <= 2)      rank_pass<2>(sqb, key64, rank);
    else if (nslots == 3) rank_pass<3>(sqb, key64, rank);
    else                  rank_pass<4>(sqb, key64, rank);

    // -------- Phase 3: scatter winners through wave-private LDS --------
    if (lane < K_NBRS) lds_col[wid][lane] = i;   // pad default: self loop
    // same-wave LDS ordering is guaranteed; no cross-wave sharing -> no barrier
#pragma unroll
    for (int c = 0; c < MAX_SLOTS; ++c) {
        if (sqb[c] != INVALID_SQB && rank[c] < K_NBRS)
            lds_col[wid][rank[c]] = s + lane + (c << 6);
    }

    const int NK = N_ATOMS * K_NBRS;
    if (lane < K_NBRS) {
        const int j = lds_col[wid][lane];
        const bool real = (j != i);
        float w = 0.0f;
        if (real) {
            // exact ref weight: d = pos[i]-pos[j]; sqrt(max(((dx^2+dy^2)+dz^2),1e-12))
            const float xj = pos[3 * j + 0];
            const float yj = pos[3 * j + 1];
            const float zj = pos[3 * j + 2];
            const float dx = __fsub_rn(xi, xj);
            const float dy = __fsub_rn(yi, yj);
            const float dz = __fsub_rn(zi, zj);
            const float s2 = __fadd_rn(__fadd_rn(__fmul_rn(dx, dx),
                                                 __fmul_rn(dy, dy)),
                                       __fmul_rn(dz, dz));
            w = __fsqrt_rn(fmaxf(s2, 1e-12f));
        }
        const int o = i * K_NBRS + lane;
        out[o]          = (float)i;           // row
        out[NK + o]     = (float)j;           // col
        out[2 * NK + o] = w;                  // weight
        out[3 * NK + o] = real ? 1.0f : 0.0f; // mask
    }
}

extern "C" void kernel_launch(void* const* d_in, const int* in_sizes, int n_in,
                              void* d_out, int out_size, void* d_ws, size_t ws_size,
                              hipStream_t stream) {
    const float* pos   = (const float*)d_in[0];
    const int*   batch = (const int*)d_in[1];
    float*       out   = (float*)d_out;

    radius_graph_kernel<<<N_ATOMS / 4, 256, 0, stream>>>(pos, batch, out);
}